// Round 14
// baseline (406.636 us; speedup 1.0000x reference)
//
#include <hip/hip_runtime.h>
#include <hip/hip_bf16.h>

#define NN 8192
#define FIN 256
#define FO 128
#define BROWS 16                // rows per k_attn block
#define NCH 32                  // 256-col chunks (NN/256)
#define L2E 1.4426950408889634f
#define C2  0.28853900817779268f   // 0.2 * log2(e)

typedef __bf16 bf16x8 __attribute__((ext_vector_type(8)));
typedef __bf16 bf16x2 __attribute__((ext_vector_type(2)));
typedef float  f32x4  __attribute__((ext_vector_type(4)));
typedef unsigned long long u64;
typedef u64 u64x2 __attribute__((ext_vector_type(2)));

__device__ __forceinline__ f32x4 ntload(const float* p) {
  return __builtin_nontemporal_load((const f32x4*)p);
}

// ---------------------------------------------------------------------------
// Kernel 1: h = x@W (fp32 accum), write Bpack (bf16 MFMA-B-fragment layout),
//           f_src = h@a_src, f_dst = h@a_dst (fp32).  (unchanged, proven)
// ---------------------------------------------------------------------------
__global__ __launch_bounds__(256) void k_proj(
    const float* __restrict__ x, const float* __restrict__ W,
    const float* __restrict__ a_src, const float* __restrict__ a_dst,
    __bf16* __restrict__ Bp, float* __restrict__ f_src, float* __restrict__ f_dst)
{
  __shared__ float xs[16 * FIN];     // 16 KB x-tile
  __shared__ float fs[16], fd[16];
  const int tid = threadIdx.x;
  const int i0 = blockIdx.x * 16;

  const float4* xg = (const float4*)(x + (size_t)i0 * FIN);
  float4* xs4 = (float4*)xs;
  #pragma unroll
  for (int t = 0; t < 4; t++) xs4[tid + 256 * t] = xg[tid + 256 * t];
  if (tid < 16) { fs[tid] = 0.f; fd[tid] = 0.f; }
  __syncthreads();

  const int cq = tid & 31;    // column quad: cols c0..c0+3
  const int rg = tid >> 5;    // row group: rows r0, r0+1
  const int c0 = cq * 4;
  const int r0 = rg * 2;
  float acc0[4] = {0.f,0.f,0.f,0.f};
  float acc1[4] = {0.f,0.f,0.f,0.f};
  const float* xr0 = xs + r0 * FIN;
  const float* xr1 = xs + (r0 + 1) * FIN;

  for (int k = 0; k < FIN; k += 4) {
    float4 xa = *(const float4*)(xr0 + k);
    float4 xb = *(const float4*)(xr1 + k);
    #pragma unroll
    for (int kk = 0; kk < 4; kk++) {
      float4 wv = *(const float4*)(W + (size_t)(k + kk) * FO + c0);
      float xav = ((const float*)&xa)[kk];
      float xbv = ((const float*)&xb)[kk];
      acc0[0] += xav * wv.x; acc0[1] += xav * wv.y;
      acc0[2] += xav * wv.z; acc0[3] += xav * wv.w;
      acc1[0] += xbv * wv.x; acc1[1] += xbv * wv.y;
      acc1[2] += xbv * wv.z; acc1[3] += xbv * wv.w;
    }
  }

  float4 as = *(const float4*)(a_src + c0);
  float4 ad = *(const float4*)(a_dst + c0);
  float ps0 = acc0[0]*as.x + acc0[1]*as.y + acc0[2]*as.z + acc0[3]*as.w;
  float ps1 = acc1[0]*as.x + acc1[1]*as.y + acc1[2]*as.z + acc1[3]*as.w;
  float pd0 = acc0[0]*ad.x + acc0[1]*ad.y + acc0[2]*ad.z + acc0[3]*ad.w;
  float pd1 = acc1[0]*ad.x + acc1[1]*ad.y + acc1[2]*ad.z + acc1[3]*ad.w;
  atomicAdd(&fs[r0],     ps0);
  atomicAdd(&fs[r0 + 1], ps1);
  atomicAdd(&fd[r0],     pd0);
  atomicAdd(&fd[r0 + 1], pd1);

  const int j0 = i0 + r0;
  const int kg = j0 >> 5;
  const int q  = (j0 >> 3) & 3;
  const int t0 = j0 & 7;
  #pragma unroll
  for (int c = 0; c < 4; c++) {
    const int n = c0 + c;
    bf16x2 v;
    v[0] = (__bf16)acc0[c];
    v[1] = (__bf16)acc1[c];
    size_t idx = ((size_t)(kg * 8 + (n >> 4)) * 64 + q * 16 + (n & 15)) * 8 + t0;
    *(bf16x2*)(Bp + idx) = v;
  }
  __syncthreads();
  if (tid < 16) { f_src[i0 + tid] = fs[tid]; f_dst[i0 + tid] = fd[tid]; }
}

// ---------------------------------------------------------------------------
// Kernel 2: pipelined pack+consume P@H, 16-row blocks x 2 blocks/CU.
// Round-13 diagnosis: barrier lockstep at 1 block/CU serializes phases
// (VALU phase idles L2; MFMA phase idles VALU) -> chunk time = sum of phase
// critical paths (~2300cy) on top of HBM 3200cy. Fix: 8-wave 512-thr blocks,
// grid 512 = 2 blocks/CU; co-resident blocks aren't barrier-synced, so one
// block's phase A overlaps the other's phase B. Enabler: whole-row G tables
// (64 KB -> forced 1 blk/CU) replaced by per-chunk G dbuf (4 KB), built one
// chunk ahead with the f_dst value register-prefetched (L2 read + exp2 hide
// in pack phase). Core arithmetic identical to r13 (phase A frags, bit
// addressing, zero-redundancy phase B per wave). LDS ~13 KB, ~70 VGPR.
// Per-chunk-pair budget/CU: HBM 3200 > L2 2300 > LDS 1200 > VALU 1000.
// ---------------------------------------------------------------------------
__global__ __launch_bounds__(512, 4) void k_attn(
    const float* __restrict__ adj, const __bf16* __restrict__ Bp,
    const float* __restrict__ f_src, const float* __restrict__ f_dst,
    float* __restrict__ out)
{
  __shared__ __align__(16) float G1s[2][256];            // 2 KB (dbuf)
  __shared__ __align__(16) float G2s[2][256];            // 2 KB
  __shared__ __align__(16) u64 msk[BROWS][6];            // 768 B (pad: 2-way max)
  __shared__ __align__(16) __bf16 af[8][64][8];          // 8 KB a-frags
  __shared__ float lsum[BROWS];

  const int tid = threadIdx.x;
  const int w = tid >> 6;             // 0..7
  const int lane = tid & 63;
  const int m = lane & 15;
  const int q = lane >> 4;
  const int i0 = blockIdx.x * BROWS;

  // phase-A role: frag fA = w -> (sqA, kgA); phase-B role: nq8 = w
  const int sqA = w >> 1, kgA = w & 1;
  const int nq8 = w;
  // G-builder role: table tbl = tid>>8, column gcol = tid&255
  const int tbl = tid >> 8, gcol = tid & 255;

  // ---- prologue: issue chunk-0/1 adj loads FIRST.
  // Wave w owns rows 2w, 2w+1; each marches sequentially chunk-to-chunk.
  const float* abase = adj + (size_t)(i0 + 2 * w) * NN + lane * 4;
  f32x4 sA0 = ntload(abase);
  f32x4 sA1 = ntload(abase + NN);
  f32x4 sB0 = ntload(abase + 256);
  f32x4 sB1 = ntload(abase + NN + 256);

  // G(0) tables + register-prefetch f_dst for G(1)
  {
    float d0 = f_dst[gcol];
    if (tbl == 0) G1s[0][gcol] = __builtin_amdgcn_exp2f(d0 * L2E);
    else          G2s[0][gcol] = __builtin_amdgcn_exp2f(d0 * C2);
  }
  float fdv = f_dst[256 + gcol];      // for G(1), written at pack(0)
  if (tid < BROWS) lsum[tid] = 0.f;
  float s = f_src[i0 + m];
  const float F1 = __builtin_amdgcn_exp2f(s * L2E);
  const float F2 = __builtin_amdgcn_exp2f(s * C2);

  f32x4 acc = (f32x4){0.f, 0.f, 0.f, 0.f};
  float psum = 0.f;

#define ITER(c, s0, s1)                                                       \
  {                                                                           \
    /* pack chunk c (ballot regs loaded 2 iters ago) + write G(c+1) */        \
    u64 b0 = __ballot(s0[0] > 0.f), b1 = __ballot(s0[1] > 0.f);               \
    u64 b2 = __ballot(s0[2] > 0.f), b3 = __ballot(s0[3] > 0.f);               \
    if (lane < 4) msk[2*w][lane]   = lane==0?b0:lane==1?b1:lane==2?b2:b3;     \
    b0 = __ballot(s1[0] > 0.f); b1 = __ballot(s1[1] > 0.f);                   \
    b2 = __ballot(s1[2] > 0.f); b3 = __ballot(s1[3] > 0.f);                   \
    if (lane < 4) msk[2*w+1][lane] = lane==0?b0:lane==1?b1:lane==2?b2:b3;     \
    if ((c) + 1 < NCH) {                                                      \
      if (tbl == 0) G1s[((c)+1)&1][gcol] = __builtin_amdgcn_exp2f(fdv * L2E); \
      else          G2s[((c)+1)&1][gcol] = __builtin_amdgcn_exp2f(fdv * C2);  \
    }                                                                         \
    __syncthreads();   /* bar1: msk(c) + G(c) visible */                      \
    /* phase A: my ONE frag (sqA, kgA), computed once per block */            \
    {                                                                         \
      u64x2 Ma = *(const u64x2*)&msk[m][0];                                   \
      u64x2 Mb = *(const u64x2*)&msk[m][2];                                   \
      const u64 M0 = Ma[0], M1 = Ma[1], M2 = Mb[0], M3 = Mb[1];               \
      const int jl = sqA * 64 + kgA * 32 + q * 8;                             \
      float4 u0 = *(const float4*)(&G1s[(c)&1][jl]);                          \
      float4 u1 = *(const float4*)(&G1s[(c)&1][jl + 4]);                      \
      float4 v0 = *(const float4*)(&G2s[(c)&1][jl]);                          \
      float4 v1 = *(const float4*)(&G2s[(c)&1][jl + 4]);                      \
      const unsigned b = sqA * 16 + kgA * 8 + q * 2;                          \
      const unsigned e0 = (unsigned)(M0 >> b);                                \
      const unsigned e1 = (unsigned)(M1 >> b);                                \
      const unsigned e2 = (unsigned)(M2 >> b);                                \
      const unsigned e3 = (unsigned)(M3 >> b);                                \
      float p0 = (e0 & 1u) ? fmaxf(F1 * u0.x, F2 * v0.x) : 0.f;               \
      float p1 = (e1 & 1u) ? fmaxf(F1 * u0.y, F2 * v0.y) : 0.f;               \
      float p2 = (e2 & 1u) ? fmaxf(F1 * u0.z, F2 * v0.z) : 0.f;               \
      float p3 = (e3 & 1u) ? fmaxf(F1 * u0.w, F2 * v0.w) : 0.f;               \
      float p4 = (e0 & 2u) ? fmaxf(F1 * u1.x, F2 * v1.x) : 0.f;               \
      float p5 = (e1 & 2u) ? fmaxf(F1 * u1.y, F2 * v1.y) : 0.f;               \
      float p6 = (e2 & 2u) ? fmaxf(F1 * u1.z, F2 * v1.z) : 0.f;               \
      float p7 = (e3 & 2u) ? fmaxf(F1 * u1.w, F2 * v1.w) : 0.f;               \
      psum += ((p0 + p1) + (p2 + p3)) + ((p4 + p5) + (p6 + p7));              \
      bf16x8 a;                                                               \
      a[0] = (__bf16)p0; a[1] = (__bf16)p1; a[2] = (__bf16)p2;                \
      a[3] = (__bf16)p3; a[4] = (__bf16)p4; a[5] = (__bf16)p5;                \
      a[6] = (__bf16)p6; a[7] = (__bf16)p7;                                   \
      *(bf16x8*)&af[w][lane][0] = a;                                          \
    }                                                                         \
    __syncthreads();   /* bar2: af(c) ready */                                \
    /* phase B: my nq8 slice x all 8 frags; Bp loads 8-deep */                \
    {                                                                         \
      const __bf16* bch = Bp + (size_t)(c) * 8 * 4096                         \
                          + (size_t)nq8 * 512 + lane * 8;                     \
      bf16x8 bf0 = *(const bf16x8*)(bch);                                     \
      bf16x8 bf1 = *(const bf16x8*)(bch + 4096);                              \
      bf16x8 bf2 = *(const bf16x8*)(bch + 2 * 4096);                          \
      bf16x8 bf3 = *(const bf16x8*)(bch + 3 * 4096);                          \
      bf16x8 bf4 = *(const bf16x8*)(bch + 4 * 4096);                          \
      bf16x8 bf5 = *(const bf16x8*)(bch + 5 * 4096);                          \
      bf16x8 bf6 = *(const bf16x8*)(bch + 6 * 4096);                          \
      bf16x8 bf7 = *(const bf16x8*)(bch + 7 * 4096);                          \
      bf16x8 a0 = *(const bf16x8*)&af[0][lane][0];                            \
      bf16x8 a1 = *(const bf16x8*)&af[1][lane][0];                            \
      bf16x8 a2 = *(const bf16x8*)&af[2][lane][0];                            \
      bf16x8 a3 = *(const bf16x8*)&af[3][lane][0];                            \
      bf16x8 a4 = *(const bf16x8*)&af[4][lane][0];                            \
      bf16x8 a5 = *(const bf16x8*)&af[5][lane][0];                            \
      bf16x8 a6 = *(const bf16x8*)&af[6][lane][0];                            \
      bf16x8 a7 = *(const bf16x8*)&af[7][lane][0];                            \
      acc = __builtin_amdgcn_mfma_f32_16x16x32_bf16(a0, bf0, acc, 0, 0, 0);   \
      acc = __builtin_amdgcn_mfma_f32_16x16x32_bf16(a1, bf1, acc, 0, 0, 0);   \
      acc = __builtin_amdgcn_mfma_f32_16x16x32_bf16(a2, bf2, acc, 0, 0, 0);   \
      acc = __builtin_amdgcn_mfma_f32_16x16x32_bf16(a3, bf3, acc, 0, 0, 0);   \
      acc = __builtin_amdgcn_mfma_f32_16x16x32_bf16(a4, bf4, acc, 0, 0, 0);   \
      acc = __builtin_amdgcn_mfma_f32_16x16x32_bf16(a5, bf5, acc, 0, 0, 0);   \
      acc = __builtin_amdgcn_mfma_f32_16x16x32_bf16(a6, bf6, acc, 0, 0, 0);   \
      acc = __builtin_amdgcn_mfma_f32_16x16x32_bf16(a7, bf7, acc, 0, 0, 0);   \
    }                                                                         \
    /* refill: chunk c+2 adj + f_dst for G(c+2); youngest vmem, no FIFO trap */ \
    if ((c) + 2 < NCH) {                                                      \
      s0 = ntload(abase + ((c) + 2) * 256);                                   \
      s1 = ntload(abase + NN + ((c) + 2) * 256);                              \
      fdv = f_dst[((c) + 2) * 256 + gcol];                                    \
    }                                                                         \
  }

  for (int c = 0; c < NCH; c += 2) {
    ITER(c, sA0, sA1)
    ITER(c + 1, sB0, sB1)
  }
#undef ITER

  // ---- epilogue: denominators (8 frag-waves per row), direct divided output
  {
    float p = psum;
    p += __shfl_xor(p, 16);
    p += __shfl_xor(p, 32);
    if (lane < 16) atomicAdd(&lsum[lane], p);
  }
  __syncthreads();

  #pragma unroll
  for (int r = 0; r < 4; ++r) {
    const int rr = q * 4 + r;                    // row within block
    const float inv = 1.0f / lsum[rr];
    out[(size_t)(i0 + rr) * FO + nq8 * 16 + m] = acc[r] * inv;
  }
}

extern "C" void kernel_launch(void* const* d_in, const int* in_sizes, int n_in,
                              void* d_out, int out_size, void* d_ws, size_t ws_size,
                              hipStream_t stream) {
  const float* x     = (const float*)d_in[0];
  const float* adj   = (const float*)d_in[1];
  const float* W     = (const float*)d_in[2];
  const float* a_src = (const float*)d_in[3];
  const float* a_dst = (const float*)d_in[4];
  float* out = (float*)d_out;

  char* ws = (char*)d_ws;
  __bf16* Bp   = (__bf16*)ws;                      // 0 .. 2 MB
  float* f_src = (float*)(ws + 2097152);           // 32 KB
  float* f_dst = (float*)(ws + 2097152 + 32768);   // 32 KB

  hipLaunchKernelGGL(k_proj, dim3(512), dim3(256), 0, stream,
                     x, W, a_src, a_dst, Bp, f_src, f_dst);
  hipLaunchKernelGGL(k_attn, dim3(512), dim3(512), 0, stream,
                     adj, Bp, f_src, f_dst, out);
}